// Round 1
// baseline (1309.325 us; speedup 1.0000x reference)
//
#include <hip/hip_runtime.h>
#include <math.h>

// Problem constants
// B=8, S=2048, N=16384 tokens, D=1024, H=16, HD=64, E=64, 4E=256, K=2

__device__ __forceinline__ float gelu_exact(float x) {
    return 0.5f * x * (1.0f + erff(x * 0.70710678118654752f));
}

// ---------------------------------------------------------------------------
// K1: k/v projections of expert embeddings.
// C[row(0..2047)][e(0..63)] = dot(in_proj_w[1024+row], ee[e]) + in_proj_b[1024+row]
// row<1024 -> kbuf, else vbuf; layout dst[h][e][hd] (h=j/64, hd=j%64, j=row%1024)
// ---------------------------------------------------------------------------
__global__ __launch_bounds__(256) void kv_kernel(
    const float* __restrict__ w, const float* __restrict__ b,
    const float* __restrict__ ee, float* __restrict__ kbuf, float* __restrict__ vbuf) {
    __shared__ float As[32][68];
    __shared__ float Bs[32][68];
    int tid = threadIdx.x;
    int r0 = blockIdx.x * 64;           // 32 blocks x 64 rows
    int tx = tid & 15, ty = tid >> 4;
    float acc[4][4] = {};
    const float* wbase = w + (size_t)(1024 + r0) * 1024;
    for (int k0 = 0; k0 < 1024; k0 += 32) {
        #pragma unroll
        for (int i = 0; i < 2; i++) {
            int f = tid + i * 256;      // 0..511
            int row = f >> 3, c4 = f & 7;
            float4 v = *(const float4*)(wbase + (size_t)row * 1024 + k0 + c4 * 4);
            As[c4*4+0][row] = v.x; As[c4*4+1][row] = v.y;
            As[c4*4+2][row] = v.z; As[c4*4+3][row] = v.w;
            float4 u = *(const float4*)(ee + (size_t)row * 1024 + k0 + c4 * 4);
            Bs[c4*4+0][row] = u.x; Bs[c4*4+1][row] = u.y;
            Bs[c4*4+2][row] = u.z; Bs[c4*4+3][row] = u.w;
        }
        __syncthreads();
        #pragma unroll
        for (int kk = 0; kk < 32; kk++) {
            float a[4], bb[4];
            *(float4*)&a[0]  = *(const float4*)&As[kk][ty * 4];
            *(float4*)&bb[0] = *(const float4*)&Bs[kk][tx * 4];
            #pragma unroll
            for (int i = 0; i < 4; i++)
                #pragma unroll
                for (int j = 0; j < 4; j++)
                    acc[i][j] = fmaf(a[i], bb[j], acc[i][j]);
        }
        __syncthreads();
    }
    #pragma unroll
    for (int i = 0; i < 4; i++) {
        int row = r0 + ty * 4 + i;            // 0..2047 combined
        float bias = b[1024 + row];
        int j = row & 1023;
        int h = j >> 6, hd = j & 63;
        float* dst = (row < 1024) ? kbuf : vbuf;
        #pragma unroll
        for (int jj = 0; jj < 4; jj++) {
            int e = tx * 4 + jj;
            dst[h * 4096 + e * 64 + hd] = acc[i][jj] + bias;
        }
    }
}

// ---------------------------------------------------------------------------
// K2/K4/K5: C[M x N] = A[M x K] @ Bw[N x K]^T + bias, optional exact GELU.
// 128x128 tile, BK=32, 256 threads, 8x8 micro-tile per thread.
// ---------------------------------------------------------------------------
template<int GELU>
__global__ __launch_bounds__(256) void sgemm128(
    const float* __restrict__ A, const float* __restrict__ Bw,
    const float* __restrict__ bias, float* __restrict__ C,
    int Kdim, int ldc) {
    __shared__ float As[32][132];
    __shared__ float Bs[32][132];
    int tid = threadIdx.x;
    int m0 = blockIdx.y * 128, n0 = blockIdx.x * 128;
    int tx = tid & 15, ty = tid >> 4;
    float acc[8][8] = {};
    const float* Ab = A + (size_t)m0 * Kdim;
    const float* Bb = Bw + (size_t)n0 * Kdim;
    for (int k0 = 0; k0 < Kdim; k0 += 32) {
        #pragma unroll
        for (int i = 0; i < 4; i++) {
            int f = tid + i * 256;            // 0..1023
            int row = f >> 3, c4 = f & 7;
            float4 v = *(const float4*)(Ab + (size_t)row * Kdim + k0 + c4 * 4);
            As[c4*4+0][row] = v.x; As[c4*4+1][row] = v.y;
            As[c4*4+2][row] = v.z; As[c4*4+3][row] = v.w;
            float4 u = *(const float4*)(Bb + (size_t)row * Kdim + k0 + c4 * 4);
            Bs[c4*4+0][row] = u.x; Bs[c4*4+1][row] = u.y;
            Bs[c4*4+2][row] = u.z; Bs[c4*4+3][row] = u.w;
        }
        __syncthreads();
        #pragma unroll
        for (int kk = 0; kk < 32; kk++) {
            float a[8], bb[8];
            *(float4*)&a[0]  = *(const float4*)&As[kk][ty * 4];
            *(float4*)&a[4]  = *(const float4*)&As[kk][64 + ty * 4];
            *(float4*)&bb[0] = *(const float4*)&Bs[kk][tx * 4];
            *(float4*)&bb[4] = *(const float4*)&Bs[kk][64 + tx * 4];
            #pragma unroll
            for (int i = 0; i < 8; i++)
                #pragma unroll
                for (int j = 0; j < 8; j++)
                    acc[i][j] = fmaf(a[i], bb[j], acc[i][j]);
        }
        __syncthreads();
    }
    #pragma unroll
    for (int mi = 0; mi < 8; mi++) {
        int m = m0 + ((mi < 4) ? (ty * 4 + mi) : (64 + ty * 4 + mi - 4));
        float* crow = C + (size_t)m * ldc + n0;
        float r[8];
        #pragma unroll
        for (int j = 0; j < 8; j++) {
            int n = (j < 4) ? (tx * 4 + j) : (64 + tx * 4 + j - 4);
            float val = acc[mi][j] + bias[n0 + n];
            if (GELU) val = gelu_exact(val);
            r[j] = val;
        }
        *(float4*)(crow + tx * 4)      = *(float4*)&r[0];
        *(float4*)(crow + 64 + tx * 4) = *(float4*)&r[4];
    }
}

// ---------------------------------------------------------------------------
// K3: cross-attention. One wave (64 threads) per (b, h, 64-token tile).
// lane e holds K[e][0..63] in regs; lane d holds V^T[d][0..63] in regs.
// Softmax across the wave (one expert per lane). O overwrites Q in-place.
// ---------------------------------------------------------------------------
__global__ __launch_bounds__(64) void attn_kernel(
    const float* __restrict__ kbuf, const float* __restrict__ vbuf,
    float* __restrict__ q) {
    __shared__ float qs[64][68];
    __shared__ float ps[64];
    int l = threadIdx.x;
    int blk = blockIdx.x;
    int b = blk >> 9;
    int h = (blk >> 5) & 15;
    int st = (blk & 31) * 64;

    float4 kr[16];
    const float4* kb4 = (const float4*)(kbuf + h * 4096 + l * 64);
    #pragma unroll
    for (int i = 0; i < 16; i++) kr[i] = kb4[i];

    float vt[64];
    #pragma unroll
    for (int e = 0; e < 64; e++) vt[e] = vbuf[h * 4096 + e * 64 + l];

    float* qrowbase = q + ((size_t)(b * 2048 + st)) * 1024 + h * 64;
    #pragma unroll
    for (int it = 0; it < 16; it++) {
        int idx = l + 64 * it;             // 0..1023
        int t = idx >> 4, c4 = idx & 15;
        float4 v = *(const float4*)(qrowbase + (size_t)t * 1024 + c4 * 4);
        *(float4*)&qs[t][c4 * 4] = v;
    }
    __syncthreads();

    for (int t = 0; t < 64; t++) {
        float s = 0.f;
        #pragma unroll
        for (int i = 0; i < 16; i++) {
            float4 qv = *(const float4*)&qs[t][i * 4];
            s = fmaf(qv.x, kr[i].x, s);
            s = fmaf(qv.y, kr[i].y, s);
            s = fmaf(qv.z, kr[i].z, s);
            s = fmaf(qv.w, kr[i].w, s);
        }
        s *= 0.125f;                        // 1/sqrt(64)
        float m = s;
        #pragma unroll
        for (int off = 32; off; off >>= 1) m = fmaxf(m, __shfl_xor(m, off, 64));
        float ex = __expf(s - m);
        float sum = ex;
        #pragma unroll
        for (int off = 32; off; off >>= 1) sum += __shfl_xor(sum, off, 64);
        float p = ex / sum;
        ps[l] = p;
        __syncthreads();
        float o = 0.f;
        #pragma unroll
        for (int i = 0; i < 16; i++) {
            float4 pv = *(const float4*)&ps[i * 4];
            o = fmaf(pv.x, vt[i * 4 + 0], o);
            o = fmaf(pv.y, vt[i * 4 + 1], o);
            o = fmaf(pv.z, vt[i * 4 + 2], o);
            o = fmaf(pv.w, vt[i * 4 + 3], o);
        }
        qrowbase[(size_t)t * 1024 + l] = o;
        __syncthreads();
    }
}

// ---------------------------------------------------------------------------
// K6: gate2 + softmax + top-2 + weight normalization. 64 threads = 64 tokens.
// out[0..32767] = idx (as float), out[32768..65535] = weights.
// ---------------------------------------------------------------------------
__global__ __launch_bounds__(64) void gate_kernel(
    const float* __restrict__ h1, const float* __restrict__ w2,
    const float* __restrict__ b2, float* __restrict__ out) {
    __shared__ float w2s[64][256];
    __shared__ float b2s[64];
    int tid = threadIdx.x;
    const float4* w24 = (const float4*)w2;
    float4* w2s4 = (float4*)w2s;
    #pragma unroll
    for (int i = 0; i < 64; i++) w2s4[tid + i * 64] = w24[tid + i * 64];
    b2s[tid] = b2[tid];
    __syncthreads();

    int tok = blockIdx.x * 64 + tid;
    const float4* hrow = (const float4*)(h1 + (size_t)tok * 256);
    float logit[64];
    #pragma unroll
    for (int e = 0; e < 64; e++) logit[e] = b2s[e];
    for (int j4 = 0; j4 < 64; j4++) {
        float4 hv = hrow[j4];
        #pragma unroll
        for (int e = 0; e < 64; e++) {
            float4 wv = *(const float4*)&w2s[e][j4 * 4];
            float acc = logit[e];
            acc = fmaf(hv.x, wv.x, acc);
            acc = fmaf(hv.y, wv.y, acc);
            acc = fmaf(hv.z, wv.z, acc);
            acc = fmaf(hv.w, wv.w, acc);
            logit[e] = acc;
        }
    }
    float mx = logit[0];
    #pragma unroll
    for (int e = 1; e < 64; e++) mx = fmaxf(mx, logit[e]);
    float pr[64];
    float sum = 0.f;
    #pragma unroll
    for (int e = 0; e < 64; e++) { pr[e] = expf(logit[e] - mx); sum += pr[e]; }
    float inv = 1.0f / sum;
    float v1 = -1.f, v2 = -1.f;
    int i1 = 0, i2 = 0;
    #pragma unroll
    for (int e = 0; e < 64; e++) {
        float p = pr[e] * inv;
        if (p > v1) { v2 = v1; i2 = i1; v1 = p; i1 = e; }
        else if (p > v2) { v2 = p; i2 = e; }
    }
    float wsum = v1 + v2 + 1e-8f;
    ((float2*)out)[tok] = make_float2((float)i1, (float)i2);
    ((float2*)(out + 32768))[tok] = make_float2(v1 / wsum, v2 / wsum);
}

// ---------------------------------------------------------------------------
extern "C" void kernel_launch(void* const* d_in, const int* in_sizes, int n_in,
                              void* d_out, int out_size, void* d_ws, size_t ws_size,
                              hipStream_t stream) {
    const float* x   = (const float*)d_in[0];
    const float* ee  = (const float*)d_in[1];
    const float* ipw = (const float*)d_in[2];
    const float* ipb = (const float*)d_in[3];
    const float* opw = (const float*)d_in[4];
    const float* opb = (const float*)d_in[5];
    const float* gw1 = (const float*)d_in[6];
    const float* gb1 = (const float*)d_in[7];
    const float* gw2 = (const float*)d_in[8];
    const float* gb2 = (const float*)d_in[9];
    float* out = (float*)d_out;
    float* ws  = (float*)d_ws;

    float* kbuf = ws;                       // 65536
    float* vbuf = ws + 65536;               // 65536
    float* qbuf = ws + 131072;              // 16384*1024 (Q, overwritten by O)
    float* attn = qbuf + 16777216;          // 16384*1024
    float* h1   = attn + 16777216;          // 16384*256

    kv_kernel<<<dim3(32), dim3(256), 0, stream>>>(ipw, ipb, ee, kbuf, vbuf);
    sgemm128<0><<<dim3(8, 128), dim3(256), 0, stream>>>(x, ipw, ipb, qbuf, 1024, 1024);
    attn_kernel<<<dim3(4096), dim3(64), 0, stream>>>(kbuf, vbuf, qbuf);
    sgemm128<0><<<dim3(8, 128), dim3(256), 0, stream>>>(qbuf, opw, opb, attn, 1024, 1024);
    sgemm128<1><<<dim3(2, 128), dim3(256), 0, stream>>>(attn, gw1, gb1, h1, 1024, 256);
    gate_kernel<<<dim3(256), dim3(64), 0, stream>>>(h1, gw2, gb2, out);
}

// Round 2
// 730.004 us; speedup vs baseline: 1.7936x; 1.7936x over previous
//
#include <hip/hip_runtime.h>
#include <math.h>

// B=8, S=2048, N=16384 tokens, D=1024, H=16, HD=64, E=64, K(topk)=2
// fp32-accurate fp16-split GEMM: a = a1 + a2/4096 (a1=fp16(a), a2'=fp16((a-a1)*4096))
// C = a1b1 + (a1*b2' + a2'*b1)/4096  (drops a2b2 ~ 2^-22 relative)

typedef _Float16 h8 __attribute__((ext_vector_type(8)));
typedef _Float16 h4 __attribute__((ext_vector_type(4)));
typedef float f4 __attribute__((ext_vector_type(4)));

__device__ __forceinline__ float gelu_exact(float x) {
    return 0.5f * x * (1.0f + erff(x * 0.70710678118654752f));
}

// ---------------------------------------------------------------------------
// split2: fp32 (rows x 1024) -> fp16 (rows x 2048): [v1 | (v-v1)*4096]
// ---------------------------------------------------------------------------
__global__ __launch_bounds__(256) void split2_kernel(
    const float* __restrict__ src, _Float16* __restrict__ dst, long total) {
    long i = ((long)blockIdx.x * 256 + threadIdx.x) * 4;
    if (i >= total) return;
    f4 v = *(const f4*)(src + i);
    long row = i >> 10; int col = (int)(i & 1023);
    _Float16* d0 = dst + row * 2048 + col;
    h4 lo, hi;
    #pragma unroll
    for (int j = 0; j < 4; j++) {
        _Float16 a = (_Float16)v[j];
        lo[j] = a;
        hi[j] = (_Float16)((v[j] - (float)a) * 4096.0f);
    }
    *(h4*)d0 = lo;
    *(h4*)(d0 + 1024) = hi;
}

// ---------------------------------------------------------------------------
// K1: k/v projections of expert embeddings (fp32, tiny).
// K layout [h][e][hd]; V stored TRANSPOSED [h][hd][e].
// ---------------------------------------------------------------------------
__global__ __launch_bounds__(256) void kv_kernel(
    const float* __restrict__ w, const float* __restrict__ b,
    const float* __restrict__ ee, float* __restrict__ kbuf, float* __restrict__ vtbuf) {
    __shared__ float As[32][68];
    __shared__ float Bs[32][68];
    int tid = threadIdx.x;
    int r0 = blockIdx.x * 64;
    int tx = tid & 15, ty = tid >> 4;
    float acc[4][4] = {};
    const float* wbase = w + (size_t)(1024 + r0) * 1024;
    for (int k0 = 0; k0 < 1024; k0 += 32) {
        #pragma unroll
        for (int i = 0; i < 2; i++) {
            int f = tid + i * 256;
            int row = f >> 3, c4 = f & 7;
            float4 v = *(const float4*)(wbase + (size_t)row * 1024 + k0 + c4 * 4);
            As[c4*4+0][row] = v.x; As[c4*4+1][row] = v.y;
            As[c4*4+2][row] = v.z; As[c4*4+3][row] = v.w;
            float4 u = *(const float4*)(ee + (size_t)row * 1024 + k0 + c4 * 4);
            Bs[c4*4+0][row] = u.x; Bs[c4*4+1][row] = u.y;
            Bs[c4*4+2][row] = u.z; Bs[c4*4+3][row] = u.w;
        }
        __syncthreads();
        #pragma unroll
        for (int kk = 0; kk < 32; kk++) {
            float a[4], bb[4];
            *(float4*)&a[0]  = *(const float4*)&As[kk][ty * 4];
            *(float4*)&bb[0] = *(const float4*)&Bs[kk][tx * 4];
            #pragma unroll
            for (int i = 0; i < 4; i++)
                #pragma unroll
                for (int j = 0; j < 4; j++)
                    acc[i][j] = fmaf(a[i], bb[j], acc[i][j]);
        }
        __syncthreads();
    }
    #pragma unroll
    for (int i = 0; i < 4; i++) {
        int row = r0 + ty * 4 + i;
        float bias = b[1024 + row];
        int j = row & 1023;
        int h = j >> 6, hd = j & 63;
        #pragma unroll
        for (int jj = 0; jj < 4; jj++) {
            int e = tx * 4 + jj;
            float val = acc[i][jj] + bias;
            if (row < 1024) kbuf[h * 4096 + e * 64 + hd] = val;
            else            vtbuf[h * 4096 + hd * 64 + e] = val;
        }
    }
}

// ---------------------------------------------------------------------------
// hgemm: C[M x N] = A_split(M x 2048) x B_split(N x 2048)^T + bias (+GELU)
// fp16 MFMA 16x16x32, 128x128 tile, 256 thr (4 waves as 2x2 of 64x64), BK=32.
// acc1 <- a1*b1 (k 0..1023); acc2 <- a1*b2' + a2'*b1; C = acc1 + acc2/4096.
// ---------------------------------------------------------------------------
template<int GELU>
__global__ __launch_bounds__(256, 2) void hgemm_kernel(
    const _Float16* __restrict__ A, const _Float16* __restrict__ B,
    const float* __restrict__ bias, float* __restrict__ C, int ldc) {
    __shared__ __align__(16) _Float16 As[128 * 32];
    __shared__ __align__(16) _Float16 Bl[128 * 32];
    __shared__ __align__(16) _Float16 Bh[128 * 32];
    int tid = threadIdx.x;
    int m0 = blockIdx.y * 128, n0 = blockIdx.x * 128;
    int w = tid >> 6, l = tid & 63;
    int wm = w & 1, wn = w >> 1;
    int lr = l & 15, lk = l >> 4;

    f4 acc1[4][4], acc2[4][4];
    #pragma unroll
    for (int i = 0; i < 4; i++)
        #pragma unroll
        for (int j = 0; j < 4; j++) {
            acc1[i][j] = (f4){0.f, 0.f, 0.f, 0.f};
            acc2[i][j] = (f4){0.f, 0.f, 0.f, 0.f};
        }

    int f0 = tid, f1 = tid + 256;
    int r0 = f0 >> 2, c0 = f0 & 3, r1 = f1 >> 2, c1 = f1 & 3;
    const _Float16* Ab = A + (size_t)m0 * 2048;
    const _Float16* Bb = B + (size_t)n0 * 2048;

    uint4 ua0, ua1, ub0, ub1, uc0, uc1;
    // preload phase1 kt=0: A seg0, B seg0 (Bl), B seg1 (Bh)
    ua0 = *(const uint4*)(Ab + (size_t)r0 * 2048 + c0 * 8);
    ua1 = *(const uint4*)(Ab + (size_t)r1 * 2048 + c1 * 8);
    ub0 = *(const uint4*)(Bb + (size_t)r0 * 2048 + c0 * 8);
    ub1 = *(const uint4*)(Bb + (size_t)r1 * 2048 + c1 * 8);
    uc0 = *(const uint4*)(Bb + (size_t)r0 * 2048 + 1024 + c0 * 8);
    uc1 = *(const uint4*)(Bb + (size_t)r1 * 2048 + 1024 + c1 * 8);

    // ---- phase 1: k in [0,1024): acc1 += a1*b1; acc2 += a1*b2' ----
    for (int kt = 0; kt < 32; kt++) {
        __syncthreads();
        *(uint4*)(As + f0 * 8) = ua0; *(uint4*)(As + f1 * 8) = ua1;
        *(uint4*)(Bl + f0 * 8) = ub0; *(uint4*)(Bl + f1 * 8) = ub1;
        *(uint4*)(Bh + f0 * 8) = uc0; *(uint4*)(Bh + f1 * 8) = uc1;
        __syncthreads();
        if (kt < 31) {
            int ka = (kt + 1) * 32;
            ua0 = *(const uint4*)(Ab + (size_t)r0 * 2048 + ka + c0 * 8);
            ua1 = *(const uint4*)(Ab + (size_t)r1 * 2048 + ka + c1 * 8);
            ub0 = *(const uint4*)(Bb + (size_t)r0 * 2048 + ka + c0 * 8);
            ub1 = *(const uint4*)(Bb + (size_t)r1 * 2048 + ka + c1 * 8);
            uc0 = *(const uint4*)(Bb + (size_t)r0 * 2048 + 1024 + ka + c0 * 8);
            uc1 = *(const uint4*)(Bb + (size_t)r1 * 2048 + 1024 + ka + c1 * 8);
        } else {
            // preload phase2 kt=0: A seg1, Bh <- B seg0
            ua0 = *(const uint4*)(Ab + (size_t)r0 * 2048 + 1024 + c0 * 8);
            ua1 = *(const uint4*)(Ab + (size_t)r1 * 2048 + 1024 + c1 * 8);
            uc0 = *(const uint4*)(Bb + (size_t)r0 * 2048 + c0 * 8);
            uc1 = *(const uint4*)(Bb + (size_t)r1 * 2048 + c1 * 8);
        }
        h8 af[4], blf[4], bhf[4];
        #pragma unroll
        for (int mi = 0; mi < 4; mi++)
            af[mi] = *(const h8*)(As + (wm * 64 + mi * 16 + lr) * 32 + lk * 8);
        #pragma unroll
        for (int ni = 0; ni < 4; ni++) {
            blf[ni] = *(const h8*)(Bl + (wn * 64 + ni * 16 + lr) * 32 + lk * 8);
            bhf[ni] = *(const h8*)(Bh + (wn * 64 + ni * 16 + lr) * 32 + lk * 8);
        }
        #pragma unroll
        for (int mi = 0; mi < 4; mi++)
            #pragma unroll
            for (int ni = 0; ni < 4; ni++) {
                acc1[mi][ni] = __builtin_amdgcn_mfma_f32_16x16x32_f16(af[mi], blf[ni], acc1[mi][ni], 0, 0, 0);
                acc2[mi][ni] = __builtin_amdgcn_mfma_f32_16x16x32_f16(af[mi], bhf[ni], acc2[mi][ni], 0, 0, 0);
            }
    }

    // ---- phase 2: acc2 += a2'*b1 ----
    for (int kt = 0; kt < 32; kt++) {
        __syncthreads();
        *(uint4*)(As + f0 * 8) = ua0; *(uint4*)(As + f1 * 8) = ua1;
        *(uint4*)(Bh + f0 * 8) = uc0; *(uint4*)(Bh + f1 * 8) = uc1;
        __syncthreads();
        if (kt < 31) {
            int ka = (kt + 1) * 32;
            ua0 = *(const uint4*)(Ab + (size_t)r0 * 2048 + 1024 + ka + c0 * 8);
            ua1 = *(const uint4*)(Ab + (size_t)r1 * 2048 + 1024 + ka + c1 * 8);
            uc0 = *(const uint4*)(Bb + (size_t)r0 * 2048 + ka + c0 * 8);
            uc1 = *(const uint4*)(Bb + (size_t)r1 * 2048 + ka + c1 * 8);
        }
        h8 af[4], bhf[4];
        #pragma unroll
        for (int mi = 0; mi < 4; mi++)
            af[mi] = *(const h8*)(As + (wm * 64 + mi * 16 + lr) * 32 + lk * 8);
        #pragma unroll
        for (int ni = 0; ni < 4; ni++)
            bhf[ni] = *(const h8*)(Bh + (wn * 64 + ni * 16 + lr) * 32 + lk * 8);
        #pragma unroll
        for (int mi = 0; mi < 4; mi++)
            #pragma unroll
            for (int ni = 0; ni < 4; ni++)
                acc2[mi][ni] = __builtin_amdgcn_mfma_f32_16x16x32_f16(af[mi], bhf[ni], acc2[mi][ni], 0, 0, 0);
    }

    // ---- epilogue: C/D layout col=lane&15, row=(lane>>4)*4+reg ----
    #pragma unroll
    for (int mi = 0; mi < 4; mi++)
        #pragma unroll
        for (int ni = 0; ni < 4; ni++) {
            int n = n0 + wn * 64 + ni * 16 + lr;
            float bn = bias[n];
            #pragma unroll
            for (int j = 0; j < 4; j++) {
                int m = m0 + wm * 64 + mi * 16 + lk * 4 + j;
                float val = acc1[mi][ni][j] + acc2[mi][ni][j] * (1.0f / 4096.0f) + bn;
                if (GELU) val = gelu_exact(val);
                C[(size_t)m * ldc + n] = val;
            }
        }
}

// ---------------------------------------------------------------------------
// attn2: wave-autonomous cross-attention. Each wave: one (b,h,64-token tile).
// lane = expert (scores) AND lane = hd (PV). K rows / V^T rows in registers.
// Writes O directly as fp16 split into os (M x 2048).
// ---------------------------------------------------------------------------
__global__ __launch_bounds__(256) void attn2_kernel(
    const float* __restrict__ kbuf, const float* __restrict__ vtbuf,
    const float* __restrict__ q, _Float16* __restrict__ os) {
    __shared__ __align__(16) float qs[4][64][68];
    __shared__ __align__(16) float ps[4][2][64];
    int tid = threadIdx.x;
    int w = tid >> 6, l = tid & 63;
    int wid = blockIdx.x * 4 + w;
    int b = wid >> 9, h = (wid >> 5) & 15, t0 = (wid & 31) * 64;

    f4 kr[16], vt[16];
    const f4* kp = (const f4*)(kbuf + h * 4096 + l * 64);
    const f4* vp = (const f4*)(vtbuf + h * 4096 + l * 64);
    #pragma unroll
    for (int i = 0; i < 16; i++) { kr[i] = kp[i]; vt[i] = vp[i]; }

    const float* qbase = q + ((size_t)(b * 2048 + t0)) * 1024 + h * 64;
    #pragma unroll
    for (int it = 0; it < 16; it++) {
        int f = it * 64 + l;
        int r = f >> 4, c = f & 15;
        f4 v = *(const f4*)(qbase + (size_t)r * 1024 + c * 4);
        *(f4*)&qs[w][r][c * 4] = v;
    }
    // wave-local LDS: compiler inserts lgkmcnt waits on may-alias reads below.

    for (int t = 0; t < 64; t++) {
        float s = 0.f;
        #pragma unroll
        for (int i = 0; i < 16; i++) {
            f4 qv = *(const f4*)&qs[w][t][i * 4];
            s = fmaf(qv[0], kr[i][0], s);
            s = fmaf(qv[1], kr[i][1], s);
            s = fmaf(qv[2], kr[i][2], s);
            s = fmaf(qv[3], kr[i][3], s);
        }
        s *= 0.125f;
        float ex = __expf(s);             // |s| <= ~3, no max-sub needed
        float sum = ex;
        #pragma unroll
        for (int off = 32; off; off >>= 1) sum += __shfl_xor(sum, off, 64);
        float p = ex / sum;
        ps[w][t & 1][l] = p;
        float o = 0.f;
        #pragma unroll
        for (int i = 0; i < 16; i++) {
            f4 pv = *(const f4*)&ps[w][t & 1][i * 4];
            o = fmaf(pv[0], vt[i][0], o);
            o = fmaf(pv[1], vt[i][1], o);
            o = fmaf(pv[2], vt[i][2], o);
            o = fmaf(pv[3], vt[i][3], o);
        }
        _Float16 o1 = (_Float16)o;
        _Float16 o2 = (_Float16)((o - (float)o1) * 4096.0f);
        size_t tok = (size_t)(b * 2048 + t0 + t);
        os[tok * 2048 + h * 64 + l] = o1;
        os[tok * 2048 + 1024 + h * 64 + l] = o2;
    }
}

// ---------------------------------------------------------------------------
// K6: gate2 + softmax + top-2 + weight normalization. (unchanged, fp32)
// ---------------------------------------------------------------------------
__global__ __launch_bounds__(64) void gate_kernel(
    const float* __restrict__ h1, const float* __restrict__ w2,
    const float* __restrict__ b2, float* __restrict__ out) {
    __shared__ float w2s[64][256];
    __shared__ float b2s[64];
    int tid = threadIdx.x;
    const float4* w24 = (const float4*)w2;
    float4* w2s4 = (float4*)w2s;
    #pragma unroll
    for (int i = 0; i < 64; i++) w2s4[tid + i * 64] = w24[tid + i * 64];
    b2s[tid] = b2[tid];
    __syncthreads();

    int tok = blockIdx.x * 64 + tid;
    const float4* hrow = (const float4*)(h1 + (size_t)tok * 256);
    float logit[64];
    #pragma unroll
    for (int e = 0; e < 64; e++) logit[e] = b2s[e];
    for (int j4 = 0; j4 < 64; j4++) {
        float4 hv = hrow[j4];
        #pragma unroll
        for (int e = 0; e < 64; e++) {
            float4 wv = *(const float4*)&w2s[e][j4 * 4];
            float acc = logit[e];
            acc = fmaf(hv.x, wv.x, acc);
            acc = fmaf(hv.y, wv.y, acc);
            acc = fmaf(hv.z, wv.z, acc);
            acc = fmaf(hv.w, wv.w, acc);
            logit[e] = acc;
        }
    }
    float mx = logit[0];
    #pragma unroll
    for (int e = 1; e < 64; e++) mx = fmaxf(mx, logit[e]);
    float pr[64];
    float sum = 0.f;
    #pragma unroll
    for (int e = 0; e < 64; e++) { pr[e] = expf(logit[e] - mx); sum += pr[e]; }
    float inv = 1.0f / sum;
    float v1 = -1.f, v2 = -1.f;
    int i1 = 0, i2 = 0;
    #pragma unroll
    for (int e = 0; e < 64; e++) {
        float p = pr[e] * inv;
        if (p > v1) { v2 = v1; i2 = i1; v1 = p; i1 = e; }
        else if (p > v2) { v2 = p; i2 = e; }
    }
    float wsum = v1 + v2 + 1e-8f;
    ((float2*)out)[tok] = make_float2((float)i1, (float)i2);
    ((float2*)(out + 32768))[tok] = make_float2(v1 / wsum, v2 / wsum);
}

// ---------------------------------------------------------------------------
extern "C" void kernel_launch(void* const* d_in, const int* in_sizes, int n_in,
                              void* d_out, int out_size, void* d_ws, size_t ws_size,
                              hipStream_t stream) {
    const float* x   = (const float*)d_in[0];
    const float* ee  = (const float*)d_in[1];
    const float* ipw = (const float*)d_in[2];
    const float* ipb = (const float*)d_in[3];
    const float* opw = (const float*)d_in[4];
    const float* opb = (const float*)d_in[5];
    const float* gw1 = (const float*)d_in[6];
    const float* gb1 = (const float*)d_in[7];
    const float* gw2 = (const float*)d_in[8];
    const float* gb2 = (const float*)d_in[9];
    float* out = (float*)d_out;
    char* ws = (char*)d_ws;

    // region1 (67.1MB): xs -> os -> as (sequential reuse)
    _Float16* xs    = (_Float16*)ws;                          // 16384 x 2048 fp16
    // region2 (67.1MB): qbuf -> attn_out -> h1
    float*    qbuf  = (float*)(ws + 67108864);                // 16384 x 1024 f32
    _Float16* wqs   = (_Float16*)(ws + 134217728);            // 1024 x 2048
    _Float16* opws  = (_Float16*)(ws + 138412032);            // 1024 x 2048
    _Float16* gw1s  = (_Float16*)(ws + 142606336);            // 256 x 2048
    float*    kbuf  = (float*)(ws + 143654912);               // 16x64x64
    float*    vtbuf = (float*)(ws + 143917056);               // 16x64x64 (transposed)

    // weight + activation splits
    split2_kernel<<<dim3(1024),  dim3(256), 0, stream>>>(ipw, wqs, 1048576L);
    split2_kernel<<<dim3(1024),  dim3(256), 0, stream>>>(opw, opws, 1048576L);
    split2_kernel<<<dim3(256),   dim3(256), 0, stream>>>(gw1, gw1s, 262144L);
    split2_kernel<<<dim3(16384), dim3(256), 0, stream>>>(x, xs, 16777216L);
    kv_kernel<<<dim3(32), dim3(256), 0, stream>>>(ipw, ipb, ee, kbuf, vtbuf);
    // Q = x @ wq^T + bq
    hgemm_kernel<0><<<dim3(8, 128), dim3(256), 0, stream>>>(xs, wqs, ipb, qbuf, 1024);
    // attention; writes split O into xs (os)
    attn2_kernel<<<dim3(1024), dim3(256), 0, stream>>>(kbuf, vtbuf, qbuf, xs);
    // attn_out = O @ opw^T + opb  (into qbuf region)
    hgemm_kernel<0><<<dim3(8, 128), dim3(256), 0, stream>>>(xs, opws, opb, qbuf, 1024);
    // split attn_out -> xs (as)
    split2_kernel<<<dim3(16384), dim3(256), 0, stream>>>(qbuf, xs, 16777216L);
    // h1 = gelu(attn_out @ gw1^T + gb1)  (into qbuf region, 16384x256)
    hgemm_kernel<1><<<dim3(2, 128), dim3(256), 0, stream>>>(xs, gw1s, gb1, qbuf, 256);
    // gate2 + softmax + top2
    gate_kernel<<<dim3(256), dim3(64), 0, stream>>>(qbuf, gw2, gb2, out);
}

// Round 3
// 649.326 us; speedup vs baseline: 2.0164x; 1.1242x over previous
//
#include <hip/hip_runtime.h>
#include <math.h>

// B=8, S=2048, N=16384 tokens, D=1024, H=16, HD=64, E=64, K(topk)=2
// fp32-accurate fp16-split GEMM: a = a1 + a2/4096 (a1=fp16(a), a2'=fp16((a-a1)*4096))
// C = a1b1 + (a1*b2' + a2'*b1)/4096  (drops a2b2 ~ 2^-22 relative)

typedef _Float16 h8 __attribute__((ext_vector_type(8)));
typedef _Float16 h4 __attribute__((ext_vector_type(4)));
typedef float f4 __attribute__((ext_vector_type(4)));

__device__ __forceinline__ float gelu_exact(float x) {
    return 0.5f * x * (1.0f + erff(x * 0.70710678118654752f));
}

// ---------------------------------------------------------------------------
// split2: fp32 (rows x cols) -> fp16 (rows x 2*cols): [v1 | (v-v1)*4096]
// cols = 1<<colsh
// ---------------------------------------------------------------------------
__global__ __launch_bounds__(256) void split2_kernel(
    const float* __restrict__ src, _Float16* __restrict__ dst, long total, int colsh) {
    long i = ((long)blockIdx.x * 256 + threadIdx.x) * 4;
    if (i >= total) return;
    f4 v = *(const f4*)(src + i);
    long row = i >> colsh; int col = (int)(i & ((1 << colsh) - 1));
    _Float16* d0 = dst + (row << (colsh + 1)) + col;
    h4 lo, hi;
    #pragma unroll
    for (int j = 0; j < 4; j++) {
        _Float16 a = (_Float16)v[j];
        lo[j] = a;
        hi[j] = (_Float16)((v[j] - (float)a) * 4096.0f);
    }
    *(h4*)d0 = lo;
    *(h4*)(d0 + (1 << colsh)) = hi;
}

// ---------------------------------------------------------------------------
// K1: k/v projections of expert embeddings (fp32, tiny).
// K layout [h][e][hd]; V stored TRANSPOSED [h][hd][e].
// ---------------------------------------------------------------------------
__global__ __launch_bounds__(256) void kv_kernel(
    const float* __restrict__ w, const float* __restrict__ b,
    const float* __restrict__ ee, float* __restrict__ kbuf, float* __restrict__ vtbuf) {
    __shared__ float As[32][68];
    __shared__ float Bs[32][68];
    int tid = threadIdx.x;
    int r0 = blockIdx.x * 64;
    int tx = tid & 15, ty = tid >> 4;
    float acc[4][4] = {};
    const float* wbase = w + (size_t)(1024 + r0) * 1024;
    for (int k0 = 0; k0 < 1024; k0 += 32) {
        #pragma unroll
        for (int i = 0; i < 2; i++) {
            int f = tid + i * 256;
            int row = f >> 3, c4 = f & 7;
            float4 v = *(const float4*)(wbase + (size_t)row * 1024 + k0 + c4 * 4);
            As[c4*4+0][row] = v.x; As[c4*4+1][row] = v.y;
            As[c4*4+2][row] = v.z; As[c4*4+3][row] = v.w;
            float4 u = *(const float4*)(ee + (size_t)row * 1024 + k0 + c4 * 4);
            Bs[c4*4+0][row] = u.x; Bs[c4*4+1][row] = u.y;
            Bs[c4*4+2][row] = u.z; Bs[c4*4+3][row] = u.w;
        }
        __syncthreads();
        #pragma unroll
        for (int kk = 0; kk < 32; kk++) {
            float a[4], bb[4];
            *(float4*)&a[0]  = *(const float4*)&As[kk][ty * 4];
            *(float4*)&bb[0] = *(const float4*)&Bs[kk][tx * 4];
            #pragma unroll
            for (int i = 0; i < 4; i++)
                #pragma unroll
                for (int j = 0; j < 4; j++)
                    acc[i][j] = fmaf(a[i], bb[j], acc[i][j]);
        }
        __syncthreads();
    }
    #pragma unroll
    for (int i = 0; i < 4; i++) {
        int row = r0 + ty * 4 + i;
        float bias = b[1024 + row];
        int j = row & 1023;
        int h = j >> 6, hd = j & 63;
        #pragma unroll
        for (int jj = 0; jj < 4; jj++) {
            int e = tx * 4 + jj;
            float val = acc[i][jj] + bias;
            if (row < 1024) kbuf[h * 4096 + e * 64 + hd] = val;
            else            vtbuf[h * 4096 + hd * 64 + e] = val;
        }
    }
}

// ---------------------------------------------------------------------------
// hgemm: C[M x N] = A_split(M x 2048) x B_split(N x 2048)^T + bias (+GELU)
// fp16 MFMA 16x16x32, 128x128 tile, 256 thr (2x2 waves of 64x64), BK=32.
// LDS rows padded to 40 halves (80B): slot=(5*row+lk)%8 -> 2-way (free).
// OSPLIT: write fp16 split pair (lo at n, hi at nhalf+n) instead of fp32.
// ---------------------------------------------------------------------------
template<int GELU, int OSPLIT>
__global__ __launch_bounds__(256, 2) void hgemm_kernel(
    const _Float16* __restrict__ A, const _Float16* __restrict__ B,
    const float* __restrict__ bias, void* __restrict__ Cv, int ldc, int nhalf) {
    __shared__ __align__(16) _Float16 As[128 * 40];
    __shared__ __align__(16) _Float16 Bl[128 * 40];
    __shared__ __align__(16) _Float16 Bh[128 * 40];
    int tid = threadIdx.x;
    int m0 = blockIdx.y * 128, n0 = blockIdx.x * 128;
    int w = tid >> 6, l = tid & 63;
    int wm = w & 1, wn = w >> 1;
    int lr = l & 15, lk = l >> 4;

    f4 acc1[4][4], acc2[4][4];
    #pragma unroll
    for (int i = 0; i < 4; i++)
        #pragma unroll
        for (int j = 0; j < 4; j++) {
            acc1[i][j] = (f4){0.f, 0.f, 0.f, 0.f};
            acc2[i][j] = (f4){0.f, 0.f, 0.f, 0.f};
        }

    int f0 = tid, f1 = tid + 256;
    int r0 = f0 >> 2, c0 = f0 & 3, r1 = f1 >> 2, c1 = f1 & 3;
    int s0 = r0 * 40 + c0 * 8, s1 = r1 * 40 + c1 * 8;   // padded LDS offsets
    const _Float16* Ab = A + (size_t)m0 * 2048;
    const _Float16* Bb = B + (size_t)n0 * 2048;

    uint4 ua0, ua1, ub0, ub1, uc0, uc1;
    ua0 = *(const uint4*)(Ab + (size_t)r0 * 2048 + c0 * 8);
    ua1 = *(const uint4*)(Ab + (size_t)r1 * 2048 + c1 * 8);
    ub0 = *(const uint4*)(Bb + (size_t)r0 * 2048 + c0 * 8);
    ub1 = *(const uint4*)(Bb + (size_t)r1 * 2048 + c1 * 8);
    uc0 = *(const uint4*)(Bb + (size_t)r0 * 2048 + 1024 + c0 * 8);
    uc1 = *(const uint4*)(Bb + (size_t)r1 * 2048 + 1024 + c1 * 8);

    // ---- phase 1: k in [0,1024): acc1 += a1*b1; acc2 += a1*b2' ----
    for (int kt = 0; kt < 32; kt++) {
        __syncthreads();
        *(uint4*)(As + s0) = ua0; *(uint4*)(As + s1) = ua1;
        *(uint4*)(Bl + s0) = ub0; *(uint4*)(Bl + s1) = ub1;
        *(uint4*)(Bh + s0) = uc0; *(uint4*)(Bh + s1) = uc1;
        __syncthreads();
        if (kt < 31) {
            int ka = (kt + 1) * 32;
            ua0 = *(const uint4*)(Ab + (size_t)r0 * 2048 + ka + c0 * 8);
            ua1 = *(const uint4*)(Ab + (size_t)r1 * 2048 + ka + c1 * 8);
            ub0 = *(const uint4*)(Bb + (size_t)r0 * 2048 + ka + c0 * 8);
            ub1 = *(const uint4*)(Bb + (size_t)r1 * 2048 + ka + c1 * 8);
            uc0 = *(const uint4*)(Bb + (size_t)r0 * 2048 + 1024 + ka + c0 * 8);
            uc1 = *(const uint4*)(Bb + (size_t)r1 * 2048 + 1024 + ka + c1 * 8);
        } else {
            ua0 = *(const uint4*)(Ab + (size_t)r0 * 2048 + 1024 + c0 * 8);
            ua1 = *(const uint4*)(Ab + (size_t)r1 * 2048 + 1024 + c1 * 8);
            uc0 = *(const uint4*)(Bb + (size_t)r0 * 2048 + c0 * 8);
            uc1 = *(const uint4*)(Bb + (size_t)r1 * 2048 + c1 * 8);
        }
        h8 af[4], blf[4], bhf[4];
        #pragma unroll
        for (int mi = 0; mi < 4; mi++)
            af[mi] = *(const h8*)(As + (wm * 64 + mi * 16 + lr) * 40 + lk * 8);
        #pragma unroll
        for (int ni = 0; ni < 4; ni++) {
            blf[ni] = *(const h8*)(Bl + (wn * 64 + ni * 16 + lr) * 40 + lk * 8);
            bhf[ni] = *(const h8*)(Bh + (wn * 64 + ni * 16 + lr) * 40 + lk * 8);
        }
        #pragma unroll
        for (int mi = 0; mi < 4; mi++)
            #pragma unroll
            for (int ni = 0; ni < 4; ni++) {
                acc1[mi][ni] = __builtin_amdgcn_mfma_f32_16x16x32_f16(af[mi], blf[ni], acc1[mi][ni], 0, 0, 0);
                acc2[mi][ni] = __builtin_amdgcn_mfma_f32_16x16x32_f16(af[mi], bhf[ni], acc2[mi][ni], 0, 0, 0);
            }
    }

    // ---- phase 2: acc2 += a2'*b1 ----
    for (int kt = 0; kt < 32; kt++) {
        __syncthreads();
        *(uint4*)(As + s0) = ua0; *(uint4*)(As + s1) = ua1;
        *(uint4*)(Bh + s0) = uc0; *(uint4*)(Bh + s1) = uc1;
        __syncthreads();
        if (kt < 31) {
            int ka = (kt + 1) * 32;
            ua0 = *(const uint4*)(Ab + (size_t)r0 * 2048 + 1024 + ka + c0 * 8);
            ua1 = *(const uint4*)(Ab + (size_t)r1 * 2048 + 1024 + ka + c1 * 8);
            uc0 = *(const uint4*)(Bb + (size_t)r0 * 2048 + ka + c0 * 8);
            uc1 = *(const uint4*)(Bb + (size_t)r1 * 2048 + ka + c1 * 8);
        }
        h8 af[4], bhf[4];
        #pragma unroll
        for (int mi = 0; mi < 4; mi++)
            af[mi] = *(const h8*)(As + (wm * 64 + mi * 16 + lr) * 40 + lk * 8);
        #pragma unroll
        for (int ni = 0; ni < 4; ni++)
            bhf[ni] = *(const h8*)(Bh + (wn * 64 + ni * 16 + lr) * 40 + lk * 8);
        #pragma unroll
        for (int mi = 0; mi < 4; mi++)
            #pragma unroll
            for (int ni = 0; ni < 4; ni++)
                acc2[mi][ni] = __builtin_amdgcn_mfma_f32_16x16x32_f16(af[mi], bhf[ni], acc2[mi][ni], 0, 0, 0);
    }

    // ---- epilogue: C/D layout col=lane&15, row=(lane>>4)*4+reg ----
    #pragma unroll
    for (int mi = 0; mi < 4; mi++)
        #pragma unroll
        for (int ni = 0; ni < 4; ni++) {
            int n = n0 + wn * 64 + ni * 16 + lr;
            float bn = bias[n];
            #pragma unroll
            for (int j = 0; j < 4; j++) {
                int m = m0 + wm * 64 + mi * 16 + lk * 4 + j;
                float val = acc1[mi][ni][j] + acc2[mi][ni][j] * (1.0f / 4096.0f) + bn;
                if (GELU) val = gelu_exact(val);
                if (OSPLIT) {
                    _Float16* Ch = (_Float16*)Cv;
                    _Float16 lo = (_Float16)val;
                    Ch[(size_t)m * ldc + n] = lo;
                    Ch[(size_t)m * ldc + nhalf + n] = (_Float16)((val - (float)lo) * 4096.0f);
                } else {
                    ((float*)Cv)[(size_t)m * ldc + n] = val;
                }
            }
        }
}

// ---------------------------------------------------------------------------
// attn2: wave-autonomous cross-attention. Each wave: one (b,h,64-token tile).
// lane = expert (scores) AND lane = hd (PV). K rows / V^T rows in registers.
// Writes O directly as fp16 split into os (M x 2048).
// ---------------------------------------------------------------------------
__global__ __launch_bounds__(256) void attn2_kernel(
    const float* __restrict__ kbuf, const float* __restrict__ vtbuf,
    const float* __restrict__ q, _Float16* __restrict__ os) {
    __shared__ __align__(16) float qs[4][64][68];
    __shared__ __align__(16) float ps[4][2][64];
    int tid = threadIdx.x;
    int w = tid >> 6, l = tid & 63;
    int wid = blockIdx.x * 4 + w;
    int b = wid >> 9, h = (wid >> 5) & 15, t0 = (wid & 31) * 64;

    f4 kr[16], vt[16];
    const f4* kp = (const f4*)(kbuf + h * 4096 + l * 64);
    const f4* vp = (const f4*)(vtbuf + h * 4096 + l * 64);
    #pragma unroll
    for (int i = 0; i < 16; i++) { kr[i] = kp[i]; vt[i] = vp[i]; }

    const float* qbase = q + ((size_t)(b * 2048 + t0)) * 1024 + h * 64;
    #pragma unroll
    for (int it = 0; it < 16; it++) {
        int f = it * 64 + l;
        int r = f >> 4, c = f & 15;
        f4 v = *(const f4*)(qbase + (size_t)r * 1024 + c * 4);
        *(f4*)&qs[w][r][c * 4] = v;
    }

    for (int t = 0; t < 64; t++) {
        float s = 0.f;
        #pragma unroll
        for (int i = 0; i < 16; i++) {
            f4 qv = *(const f4*)&qs[w][t][i * 4];
            s = fmaf(qv[0], kr[i][0], s);
            s = fmaf(qv[1], kr[i][1], s);
            s = fmaf(qv[2], kr[i][2], s);
            s = fmaf(qv[3], kr[i][3], s);
        }
        s *= 0.125f;
        float ex = __expf(s);
        float sum = ex;
        #pragma unroll
        for (int off = 32; off; off >>= 1) sum += __shfl_xor(sum, off, 64);
        float p = ex / sum;
        ps[w][t & 1][l] = p;
        float o = 0.f;
        #pragma unroll
        for (int i = 0; i < 16; i++) {
            f4 pv = *(const f4*)&ps[w][t & 1][i * 4];
            o = fmaf(pv[0], vt[i][0], o);
            o = fmaf(pv[1], vt[i][1], o);
            o = fmaf(pv[2], vt[i][2], o);
            o = fmaf(pv[3], vt[i][3], o);
        }
        _Float16 o1 = (_Float16)o;
        _Float16 o2 = (_Float16)((o - (float)o1) * 4096.0f);
        size_t tok = (size_t)(b * 2048 + t0 + t);
        os[tok * 2048 + h * 64 + l] = o1;
        os[tok * 2048 + 1024 + h * 64 + l] = o2;
    }
}

// ---------------------------------------------------------------------------
// gate2: logits(16384x64) = h1s(16384x[256|256]) @ gw2s(64x[256|256])^T + b2
// via 4-product split MFMA (frags straight from global/L2), then fused
// softmax + top-2 + weight normalization. Wave handles 16 tokens.
// ---------------------------------------------------------------------------
__global__ __launch_bounds__(256) void gate2_kernel(
    const _Float16* __restrict__ h1s, const _Float16* __restrict__ w2s,
    const float* __restrict__ b2, float* __restrict__ out) {
    int tid = threadIdx.x;
    int w = tid >> 6, l = tid & 63;
    int lr = l & 15, lk = l >> 4;
    int trow = blockIdx.x * 64 + w * 16;        // wave's 16 tokens

    f4 acc1[4], acc2[4], acc3[4];
    #pragma unroll
    for (int ni = 0; ni < 4; ni++) {
        acc1[ni] = (f4){0.f,0.f,0.f,0.f};
        acc2[ni] = (f4){0.f,0.f,0.f,0.f};
        acc3[ni] = (f4){0.f,0.f,0.f,0.f};
    }
    const _Float16* Arow = h1s + (size_t)(trow + lr) * 512;
    #pragma unroll
    for (int kt = 0; kt < 8; kt++) {
        h8 a1 = *(const h8*)(Arow + kt * 32 + lk * 8);
        h8 a2 = *(const h8*)(Arow + 256 + kt * 32 + lk * 8);
        #pragma unroll
        for (int ni = 0; ni < 4; ni++) {
            const _Float16* Brow = w2s + (size_t)(ni * 16 + lr) * 512;
            h8 b1 = *(const h8*)(Brow + kt * 32 + lk * 8);
            h8 bh = *(const h8*)(Brow + 256 + kt * 32 + lk * 8);
            acc1[ni] = __builtin_amdgcn_mfma_f32_16x16x32_f16(a1, b1, acc1[ni], 0, 0, 0);
            acc2[ni] = __builtin_amdgcn_mfma_f32_16x16x32_f16(a1, bh, acc2[ni], 0, 0, 0);
            acc2[ni] = __builtin_amdgcn_mfma_f32_16x16x32_f16(a2, b1, acc2[ni], 0, 0, 0);
            acc3[ni] = __builtin_amdgcn_mfma_f32_16x16x32_f16(a2, bh, acc3[ni], 0, 0, 0);
        }
    }
    float bcol[4];
    #pragma unroll
    for (int ni = 0; ni < 4; ni++) bcol[ni] = b2[ni * 16 + lr];

    const float c1 = 1.0f / 4096.0f, c2 = 1.0f / 16777216.0f;
    #pragma unroll
    for (int j = 0; j < 4; j++) {
        int tok = trow + lk * 4 + j;
        float lg[4];
        #pragma unroll
        for (int ni = 0; ni < 4; ni++)
            lg[ni] = acc1[ni][j] + acc2[ni][j] * c1 + acc3[ni][j] * c2 + bcol[ni];
        float mx = fmaxf(fmaxf(lg[0], lg[1]), fmaxf(lg[2], lg[3]));
        #pragma unroll
        for (int off = 1; off <= 8; off <<= 1) mx = fmaxf(mx, __shfl_xor(mx, off, 64));
        float pr[4], s = 0.f;
        #pragma unroll
        for (int ni = 0; ni < 4; ni++) { pr[ni] = expf(lg[ni] - mx); s += pr[ni]; }
        #pragma unroll
        for (int off = 1; off <= 8; off <<= 1) s += __shfl_xor(s, off, 64);
        float inv = 1.0f / s;
        float v1 = -1.f, v2 = -1.f; int i1 = 0, i2 = 0;
        #pragma unroll
        for (int ni = 0; ni < 4; ni++) {
            float p = pr[ni] * inv;
            int e = ni * 16 + lr;
            if (p > v1) { v2 = v1; i2 = i1; v1 = p; i1 = e; }
            else if (p > v2) { v2 = p; i2 = e; }
        }
        #pragma unroll
        for (int off = 1; off <= 8; off <<= 1) {
            float u1 = __shfl_xor(v1, off, 64); int k1 = __shfl_xor(i1, off, 64);
            float u2 = __shfl_xor(v2, off, 64); int k2 = __shfl_xor(i2, off, 64);
            if (u1 > v1) {
                if (v1 > u2) { v2 = v1; i2 = i1; } else { v2 = u2; i2 = k2; }
                v1 = u1; i1 = k1;
            } else if (u1 > v2) { v2 = u1; i2 = k1; }
        }
        if (lr == 0) {
            float wsum = v1 + v2 + 1e-8f;
            out[(size_t)tok * 2]     = (float)i1;
            out[(size_t)tok * 2 + 1] = (float)i2;
            out[32768 + (size_t)tok * 2]     = v1 / wsum;
            out[32768 + (size_t)tok * 2 + 1] = v2 / wsum;
        }
    }
}

// ---------------------------------------------------------------------------
extern "C" void kernel_launch(void* const* d_in, const int* in_sizes, int n_in,
                              void* d_out, int out_size, void* d_ws, size_t ws_size,
                              hipStream_t stream) {
    const float* x   = (const float*)d_in[0];
    const float* ee  = (const float*)d_in[1];
    const float* ipw = (const float*)d_in[2];
    const float* ipb = (const float*)d_in[3];
    const float* opw = (const float*)d_in[4];
    const float* opb = (const float*)d_in[5];
    const float* gw1 = (const float*)d_in[6];
    const float* gb1 = (const float*)d_in[7];
    const float* gw2 = (const float*)d_in[8];
    const float* gb2 = (const float*)d_in[9];
    float* out = (float*)d_out;
    char* ws = (char*)d_ws;

    // region1 (64MB): xs (x-split) -> os (O-split) -> h1s (h1-split, 16MB)
    _Float16* xs    = (_Float16*)ws;                          // 16384 x 2048 fp16
    _Float16* h1s   = (_Float16*)ws;                          // 16384 x 512 fp16 (alias)
    // region2 (64MB): qbuf (Q fp32) -> aos (attn_out split fp16)
    float*    qbuf  = (float*)(ws + 67108864);                // 16384 x 1024 f32
    _Float16* aos   = (_Float16*)(ws + 67108864);             // 16384 x 2048 fp16 (alias)
    _Float16* wqs   = (_Float16*)(ws + 134217728);            // 1024 x 2048
    _Float16* opws  = (_Float16*)(ws + 138412032);            // 1024 x 2048
    _Float16* gw1s  = (_Float16*)(ws + 142606336);            // 256 x 2048
    float*    kbuf  = (float*)(ws + 143654912);               // 16x64x64 f32
    _Float16* gw2s  = (_Float16*)(ws + 143654912);            // 64 x 512 (aliases kbuf, used after attn)
    float*    vtbuf = (float*)(ws + 143917056);               // 16x64x64 f32 (transposed)

    split2_kernel<<<dim3(1024),  dim3(256), 0, stream>>>(ipw, wqs, 1048576L, 10);
    split2_kernel<<<dim3(1024),  dim3(256), 0, stream>>>(opw, opws, 1048576L, 10);
    split2_kernel<<<dim3(256),   dim3(256), 0, stream>>>(gw1, gw1s, 262144L, 10);
    split2_kernel<<<dim3(16384), dim3(256), 0, stream>>>(x, xs, 16777216L, 10);
    kv_kernel<<<dim3(32), dim3(256), 0, stream>>>(ipw, ipb, ee, kbuf, vtbuf);
    // Q = x @ wq^T + bq (fp32 out)
    hgemm_kernel<0,0><<<dim3(8, 128), dim3(256), 0, stream>>>(xs, wqs, ipb, qbuf, 1024, 0);
    // attention; writes split O into xs
    attn2_kernel<<<dim3(1024), dim3(256), 0, stream>>>(kbuf, vtbuf, qbuf, xs);
    // gw2 split (aliases kbuf region; kbuf dead after attn2)
    split2_kernel<<<dim3(16), dim3(256), 0, stream>>>(gw2, gw2s, 16384L, 8);
    // attn_out = O @ opw^T + opb -> split fp16 directly (into region2)
    hgemm_kernel<0,1><<<dim3(8, 128), dim3(256), 0, stream>>>(xs, opws, opb, (void*)aos, 2048, 1024);
    // h1 = gelu(attn_out @ gw1^T + gb1) -> split fp16 (into region1)
    hgemm_kernel<1,1><<<dim3(2, 128), dim3(256), 0, stream>>>(aos, gw1s, gb1, (void*)h1s, 512, 256);
    // gate2 + softmax + top2
    gate2_kernel<<<dim3(256), dim3(256), 0, stream>>>(h1s, gw2s, gb2, out);
}